// Round 6
// baseline (182.863 us; speedup 1.0000x reference)
//
#include <hip/hip_runtime.h>
#include <cmath>

#define EPSF 1e-15f
#define MAXN 0.99999f            // (1 - 1e-5) / sqrt(c), c=1

// ---- workspace layout (float offsets) -------------------------------------
#define OFF_ZU1  0               // 450  normalized z1 columns [75][6]
#define OFF_P1   512             // 18   zn1[6], ch1[6], sh1[6]
#define OFF_ZU2  576             // 2400 normalized z2 columns [150][16]
#define OFF_P2   3072            // 48   zn2[16], ch2[16], sh2[16]
#define OFF_PF1  3200            // 360  znf1[120]*3
#define OFF_PF2  3584            // 252  znf2[84]*3
#define OFF_PF3  3904            // 30   znf3[10]*3
#define OFF_BUF1 4096            // [B,6,196]  = 1204224
#define OFF_BUF3 (OFF_BUF1 + 1204224)   // [B,400] = 409600

// ---- fast transcendentals -------------------------------------------------
__device__ __forceinline__ float fast_tanh_pos(float x) {   // x >= 0
    float e = __expf(-2.0f * x);
    return (1.0f - e) / (1.0f + e);
}
__device__ __forceinline__ float fast_atanh01(float x) {    // 0 <= x < 1
    return 0.5f * __logf((1.0f + x) / (1.0f - x));
}
// sinh(k * asinh(t)) = sign(t) * 0.5 * (q^k - q^-k), q = |t| + sqrt(t^2+1)
__device__ __forceinline__ float sinh_k_asinh(float t, float k) {
    float at = fabsf(t);
    float lq = __logf(at + sqrtf(fmaf(at, at, 1.0f)));
    float p = __expf(k * lq);
    float r = 0.5f * (p - 1.0f / p);
    return t < 0.f ? -r : r;
}

__device__ __forceinline__ float wave_reduce_sum(float s) {
#pragma unroll
    for (int d = 1; d < 64; d <<= 1) s += __shfl_xor(s, d);
    return s;
}

// ---------------------------------------------------------------------------
// P0: combined weight prep. One block (64 thr) per output column.
// ---------------------------------------------------------------------------
__global__ __launch_bounds__(64) void prep_kernel(
        const float* __restrict__ z1, const float* __restrict__ r1,
        const float* __restrict__ z2, const float* __restrict__ r2,
        const float* __restrict__ zf1, const float* __restrict__ rf1,
        const float* __restrict__ zf2, const float* __restrict__ rf2,
        const float* __restrict__ zf3, const float* __restrict__ rf3,
        float* __restrict__ ws) {
    int blk = blockIdx.x, lane = threadIdx.x;
    const float* z; const float* r; int Din, Dout, o;
    float* zu = nullptr; float* par;
    if (blk < 6)        { z = z1;  r = r1;  Din = 75;  Dout = 6;   o = blk;       zu = ws + OFF_ZU1; par = ws + OFF_P1; }
    else if (blk < 22)  { z = z2;  r = r2;  Din = 150; Dout = 16;  o = blk - 6;   zu = ws + OFF_ZU2; par = ws + OFF_P2; }
    else if (blk < 142) { z = zf1; r = rf1; Din = 400; Dout = 120; o = blk - 22;  par = ws + OFF_PF1; }
    else if (blk < 226) { z = zf2; r = rf2; Din = 120; Dout = 84;  o = blk - 142; par = ws + OFF_PF2; }
    else                { z = zf3; r = rf3; Din = 84;  Dout = 10;  o = blk - 226; par = ws + OFF_PF3; }
    float s = 0.f;
    for (int f = lane; f < Din; f += 64) { float w = z[f * Dout + o]; s += w * w; }
    s = wave_reduce_sum(s);
    float zn = fmaxf(sqrtf(s), EPSF);
    if (lane == 0) {
        par[o] = zn;
        par[Dout + o]     = coshf(2.0f * r[o]);
        par[2 * Dout + o] = sinhf(2.0f * r[o]);
    }
    if (zu)
        for (int f = lane; f < Din; f += 64) zu[f * Dout + o] = z[f * Dout + o] / zn;
}

// ---------------------------------------------------------------------------
// chain: expmap0(patch) -> poincare_fc -> project -> hrelu(channel), all
// in-thread.
// ---------------------------------------------------------------------------
template<int N>
__device__ __forceinline__ float chain_fast(float (&a)[N], float n2,
        const float (&zn)[N], const float (&ch)[N], const float (&sh)[N]) {
    float nn = fmaxf(sqrtf(n2), EPSF);
    float t = fast_tanh_pos(nn);
    float s = t / nn * fminf(1.0f, MAXN / fmaxf(t, EPSF));
    float cx2 = (s * s) * n2;
    float denom = fmaxf(1.0f - cx2, EPSF);
    float ys2 = 0.f;
#pragma unroll
    for (int o = 0; o < N; o++) {
        float arg = (2.0f * (s * a[o]) * ch[o] - (1.0f + cx2) * sh[o]) / denom;
        float yy = sinh_k_asinh(arg, 2.0f * zn[o]);
        a[o] = yy; ys2 += yy * yy;
    }
    float dnm = 1.0f + sqrtf(1.0f + ys2);
    float ny2 = ys2 / (dnm * dnm);
    float ny = fmaxf(sqrtf(ny2), EPSF);
    float pf = fminf(1.0f, MAXN / ny);
    float sc = pf / dnm;
    float n2b = pf * pf * ny2;
    float nb = fmaxf(sqrtf(n2b), EPSF);
    float fb = fast_atanh01(fminf(nb, 1.0f - 1e-7f)) / nb;
    float m2 = 0.f;
#pragma unroll
    for (int o = 0; o < N; o++) { float uu = fmaxf(fb * sc * a[o], 0.f); a[o] = uu; m2 += uu * uu; }
    float m = fmaxf(sqrtf(m2), EPSF);
    float tm = fast_tanh_pos(m);
    float g = tm / m * fminf(1.0f, MAXN / fmaxf(tm, EPSF));
#pragma unroll
    for (int o = 0; o < N; o++) a[o] *= g;
    return g * g * m2;
}

// ---------------------------------------------------------------------------
// K1: conv1. 1 image/block, 256 thr. Thread = pooled cell (196): computes
// its 2x2 windows in registers, pools in-thread. xv padded to stride 33
// (breaks mod-32 bank alias). No intermediate LDS staging.
// ---------------------------------------------------------------------------
__global__ __launch_bounds__(256) void conv1_kernel(const float* __restrict__ x,
        const float* __restrict__ ws, float* __restrict__ out, float ratio) {
    __shared__ float xv[3168];          // [3][32][33]
    int b = blockIdx.x, tid = threadIdx.x;
    const float* zug  = ws + OFF_ZU1;
    const float* parg = ws + OFF_P1;
    for (int i = tid; i < 3072; i += 256) {
        int c = i >> 10, rem = i & 1023;
        xv[c * 1056 + (rem >> 5) * 33 + (rem & 31)] = x[(size_t)b * 3072 + i];
    }
    __syncthreads();
    for (int p = tid; p < 1024; p += 256) {
        int base = (p >> 5) * 33 + (p & 31);
        float a0 = xv[base], a1 = xv[1056 + base], a2 = xv[2112 + base];
        float n2 = a0 * a0 + a1 * a1 + a2 * a2;
        float nn = fmaxf(sqrtf(n2), EPSF);
        float f = fast_atanh01(fminf(nn, 1.0f - 1e-7f)) / nn * ratio;
        xv[base] = a0 * f; xv[1056 + base] = a1 * f; xv[2112 + base] = a2 * f;
    }
    __syncthreads();
    if (tid >= 196) return;
    int ph = tid / 14, pw = tid % 14;
    int base0 = (2 * ph) * 33 + 2 * pw;
    float acc[4][6], n2w[4];
#pragma unroll
    for (int wi = 0; wi < 4; wi++) {
        n2w[wi] = 0.f;
#pragma unroll
        for (int o = 0; o < 6; o++) acc[wi][o] = 0.f;
    }
#pragma unroll 1
    for (int c = 0; c < 3; c++) {
        float px[6][6];
#pragma unroll
        for (int r = 0; r < 6; r++)
#pragma unroll
        for (int j = 0; j < 6; j++)
            px[r][j] = xv[c * 1056 + base0 + r * 33 + j];
#pragma unroll
        for (int fi = 0; fi < 5; fi++) {
            const float* zp = zug + (c * 5 + fi) * 30;   // wave-uniform
#pragma unroll
            for (int fj = 0; fj < 5; fj++) {
                float zw[6];
#pragma unroll
                for (int o = 0; o < 6; o++) zw[o] = zp[fj * 6 + o];
#pragma unroll
                for (int dy = 0; dy < 2; dy++)
#pragma unroll
                for (int dx = 0; dx < 2; dx++) {
                    float v = px[fi + dy][fj + dx];
                    int wi = dy * 2 + dx;
                    n2w[wi] = fmaf(v, v, n2w[wi]);
#pragma unroll
                    for (int o = 0; o < 6; o++) acc[wi][o] = fmaf(v, zw[o], acc[wi][o]);
                }
            }
        }
    }
    float zn[6], chv[6], shv[6];
#pragma unroll
    for (int o = 0; o < 6; o++) { zn[o] = parg[o]; chv[o] = parg[6 + o]; shv[o] = parg[12 + o]; }
    float best[6]; float bestn = -1.f;
#pragma unroll
    for (int wi = 0; wi < 4; wi++) {
        float hn2 = chain_fast<6>(acc[wi], n2w[wi], zn, chv, shv);
        if (hn2 > bestn) {
            bestn = hn2;
#pragma unroll
            for (int o = 0; o < 6; o++) best[o] = acc[wi][o];
        }
    }
    float* op = out + (size_t)b * 1176 + tid;
#pragma unroll
    for (int o = 0; o < 6; o++) op[o * 196] = best[o];
}

// ---------------------------------------------------------------------------
// K2: conv2 + hflatten. 2 images/block (1 wave per image), 128 thr.
// Thread = (cell, channel-half): 4 windows x 8ch in registers, pair
// reductions via __shfl_xor(.,1), pool in-thread, flatten via wave reduce.
// xv padded: row stride 15, img stride 1261.
// ---------------------------------------------------------------------------
__global__ __launch_bounds__(128) void conv2_kernel(const float* __restrict__ in,
        const float* __restrict__ ws, float* __restrict__ out,
        float ratio2, float ratio3) {
    __shared__ float xv[2522];          // 2 x ([6][14][15] + 1 pad)
    int b0 = blockIdx.x * 2, tid = threadIdx.x;
    const float* zug  = ws + OFF_ZU2;
    const float* parg = ws + OFF_P2;
    for (int i = tid; i < 2352; i += 128) {
        int img = i / 1176, rem = i % 1176;
        int c = rem / 196, pix = rem % 196;
        xv[img * 1261 + c * 210 + (pix / 14) * 15 + pix % 14] = in[(size_t)b0 * 1176 + i];
    }
    __syncthreads();
    for (int t = tid; t < 392; t += 128) {
        int img = t / 196, pix = t % 196;
        int base = img * 1261 + (pix / 14) * 15 + pix % 14;
        float a[6]; float n2 = 0.f;
#pragma unroll
        for (int c = 0; c < 6; c++) { float v = xv[base + c * 210]; a[c] = v; n2 += v * v; }
        float nn = fmaxf(sqrtf(n2), EPSF);
        float f = fast_atanh01(fminf(nn, 1.0f - 1e-7f)) / nn * ratio2;
#pragma unroll
        for (int c = 0; c < 6; c++) xv[base + c * 210] = a[c] * f;
    }
    __syncthreads();
    int img = tid >> 6, l = tid & 63;
    int cell = l >> 1, h = l & 1;
    bool act = cell < 25;
    float best[8];
    float bestn = -1.f;
    float fcell = 0.f, part = 0.f;
    if (act) {
        int base0 = img * 1261 + (2 * (cell / 5)) * 15 + 2 * (cell % 5);
        float acc[4][8], n2w[4];
#pragma unroll
        for (int wi = 0; wi < 4; wi++) {
            n2w[wi] = 0.f;
#pragma unroll
            for (int o = 0; o < 8; o++) acc[wi][o] = 0.f;
        }
#pragma unroll 1
        for (int c = 0; c < 6; c++) {
            float px[6][6];
#pragma unroll
            for (int r = 0; r < 6; r++)
#pragma unroll
            for (int j = 0; j < 6; j++)
                px[r][j] = xv[base0 + c * 210 + r * 15 + j];
#pragma unroll
            for (int fi = 0; fi < 5; fi++) {
                const float* zp = zug + (c * 5 + fi) * 80 + 8 * h;
#pragma unroll
                for (int fj = 0; fj < 5; fj++) {
                    float zw[8];
#pragma unroll
                    for (int o = 0; o < 8; o++) zw[o] = zp[fj * 16 + o];
#pragma unroll
                    for (int dy = 0; dy < 2; dy++)
#pragma unroll
                    for (int dx = 0; dx < 2; dx++) {
                        float v = px[fi + dy][fj + dx];
                        int wi = dy * 2 + dx;
                        n2w[wi] = fmaf(v, v, n2w[wi]);
#pragma unroll
                        for (int o = 0; o < 8; o++) acc[wi][o] = fmaf(v, zw[o], acc[wi][o]);
                    }
                }
            }
        }
        float zn[8], chv[8], shv[8];
#pragma unroll
        for (int o = 0; o < 8; o++) {
            zn[o]  = parg[8 * h + o];
            chv[o] = parg[16 + 8 * h + o];
            shv[o] = parg[32 + 8 * h + o];
        }
#pragma unroll
        for (int wi = 0; wi < 4; wi++) {
            float nn = fmaxf(sqrtf(n2w[wi]), EPSF);
            float t = fast_tanh_pos(nn);
            float s = t / nn * fminf(1.0f, MAXN / fmaxf(t, EPSF));
            float cx2 = (s * s) * n2w[wi];
            float denom = fmaxf(1.0f - cx2, EPSF);
            float ys2h = 0.f;
#pragma unroll
            for (int o = 0; o < 8; o++) {
                float arg = (2.0f * (s * acc[wi][o]) * chv[o] - (1.0f + cx2) * shv[o]) / denom;
                float yy = sinh_k_asinh(arg, 2.0f * zn[o]);
                acc[wi][o] = yy; ys2h += yy * yy;
            }
            float ys2 = ys2h + __shfl_xor(ys2h, 1);      // partner = other chan-half
            float dnm = 1.0f + sqrtf(1.0f + ys2);
            float ny2 = ys2 / (dnm * dnm);
            float ny = fmaxf(sqrtf(ny2), EPSF);
            float pf = fminf(1.0f, MAXN / ny);
            float sc = pf / dnm;
            float n2b = pf * pf * ny2;
            float nb = fmaxf(sqrtf(n2b), EPSF);
            float fb = fast_atanh01(fminf(nb, 1.0f - 1e-7f)) / nb;
            float m2h = 0.f;
#pragma unroll
            for (int o = 0; o < 8; o++) { float uu = fmaxf(fb * sc * acc[wi][o], 0.f); acc[wi][o] = uu; m2h += uu * uu; }
            float m2 = m2h + __shfl_xor(m2h, 1);
            float m = fmaxf(sqrtf(m2), EPSF);
            float tm = fast_tanh_pos(m);
            float g = tm / m * fminf(1.0f, MAXN / fmaxf(tm, EPSF));
            float hn2 = g * g * m2;                      // identical across h pair
            if (hn2 > bestn) {
                bestn = hn2;
#pragma unroll
                for (int o = 0; o < 8; o++) best[o] = g * acc[wi][o];
            }
        }
        // hflatten: per-cell logmap factor
        float nn = fmaxf(sqrtf(bestn), EPSF);
        fcell = fast_atanh01(fminf(nn, 1.0f - 1e-7f)) / nn * ratio3;
        if (h == 0) part = fcell * fcell * bestn;
    }
    float s = wave_reduce_sum(part);                      // wave == one image
    float nn = fmaxf(sqrtf(s), EPSF);
    float t = fast_tanh_pos(nn);
    float g = t / nn * fminf(1.0f, MAXN / fmaxf(t, EPSF));
    if (act) {
        float* op = out + (size_t)(b0 + img) * 400 + cell;
#pragma unroll
        for (int o = 0; o < 8; o++) op[(8 * h + o) * 25] = g * fcell * best[o];
    }
}

// ---------------------------------------------------------------------------
// K3: fused FC stack. One wave per batch row; 4-accumulator dots for ILP;
// layer l's output sq-norm feeds layer l+1's cx2 directly.
// ---------------------------------------------------------------------------
template<int DIN, int DOUT>
__device__ __forceinline__ float dot_col(const float* __restrict__ xr,
        const float* __restrict__ z, int col) {
    float a0 = 0.f, a1 = 0.f, a2 = 0.f, a3 = 0.f;
    for (int f = 0; f < DIN; f += 4) {
        a0 = fmaf(xr[f],     z[(f)     * DOUT + col], a0);
        a1 = fmaf(xr[f + 1], z[(f + 1) * DOUT + col], a1);
        a2 = fmaf(xr[f + 2], z[(f + 2) * DOUT + col], a2);
        a3 = fmaf(xr[f + 3], z[(f + 3) * DOUT + col], a3);
    }
    return (a0 + a1) + (a2 + a3);
}

template<int DIN, int DOUT, bool RELU>
__device__ __forceinline__ float fc_layer_wave(int lane, const float* __restrict__ xr,
        float cx2, const float* __restrict__ z, const float* __restrict__ par,
        float* __restrict__ dst) {
    int o0 = lane, o1 = lane + 64;
    bool v0 = o0 < DOUT, v1 = o1 < DOUT;
    int c0 = v0 ? o0 : 0, c1 = v1 ? o1 : 0;
    float d0 = dot_col<DIN, DOUT>(xr, z, c0);
    float d1 = (DOUT > 64) ? dot_col<DIN, DOUT>(xr, z, c1) : 0.f;
    float denom = fmaxf(1.0f - cx2, EPSF);
    float zn0 = par[c0], ch0 = par[DOUT + c0], sh0 = par[2 * DOUT + c0];
    float arg0 = (2.0f * (d0 / zn0) * ch0 - (1.0f + cx2) * sh0) / denom;
    float y0 = sinh_k_asinh(arg0, 2.0f * zn0);
    float y1 = 0.f;
    if (DOUT > 64) {
        float zn1 = par[c1], ch1 = par[DOUT + c1], sh1 = par[2 * DOUT + c1];
        float arg1 = (2.0f * (d1 / zn1) * ch1 - (1.0f + cx2) * sh1) / denom;
        y1 = sinh_k_asinh(arg1, 2.0f * zn1);
    }
    float ys2 = wave_reduce_sum((v0 ? y0 * y0 : 0.f) + (v1 ? y1 * y1 : 0.f));
    float dnm = 1.0f + sqrtf(1.0f + ys2);
    float ny2 = ys2 / (dnm * dnm);
    float ny = fmaxf(sqrtf(ny2), EPSF);
    float pf = fminf(1.0f, MAXN / ny);
    float sc = pf / dnm;
    if (!RELU) {
        if (v0) dst[o0] = sc * y0;
        if (DOUT > 64 && v1) dst[o1] = sc * y1;
        return pf * pf * ny2;
    }
    float n2b = pf * pf * ny2;
    float nb = fmaxf(sqrtf(n2b), EPSF);
    float fb = fast_atanh01(fminf(nb, 1.0f - 1e-7f)) / nb;
    float u0 = fmaxf(fb * sc * y0, 0.f);
    float u1 = fmaxf(fb * sc * y1, 0.f);
    float m2 = wave_reduce_sum((v0 ? u0 * u0 : 0.f) + (v1 ? u1 * u1 : 0.f));
    float m = fmaxf(sqrtf(m2), EPSF);
    float tm = fast_tanh_pos(m);
    float g = tm / m * fminf(1.0f, MAXN / fmaxf(tm, EPSF));
    if (v0) dst[o0] = g * u0;
    if (DOUT > 64 && v1) dst[o1] = g * u1;
    return g * g * m2;
}

__global__ __launch_bounds__(256) void fc_stack_kernel(const float* __restrict__ in,
        const float* __restrict__ zf1, const float* __restrict__ zf2,
        const float* __restrict__ zf3, const float* __restrict__ ws,
        float* __restrict__ out) {
    __shared__ float xs[4][400];
    __shared__ float h1[4][120];
    __shared__ float h2[4][84];
    int wid = threadIdx.x >> 6, lane = threadIdx.x & 63;
    int b = blockIdx.x * 4 + wid;
    float* xr = xs[wid];
    float p = 0.f;
    for (int j = lane; j < 400; j += 64) { float v = in[(size_t)b * 400 + j]; xr[j] = v; p += v * v; }
    float cx2 = wave_reduce_sum(p);
    __syncthreads();
    float cx2b = fc_layer_wave<400, 120, true >(lane, xr,      cx2,  zf1, ws + OFF_PF1, h1[wid]);
    __syncthreads();
    float cx2c = fc_layer_wave<120, 84,  true >(lane, h1[wid], cx2b, zf2, ws + OFF_PF2, h2[wid]);
    __syncthreads();
    fc_layer_wave<84, 10, false>(lane, h2[wid], cx2c, zf3, ws + OFF_PF3, out + (size_t)b * 10);
}

// ---------------------------------------------------------------------------
static double beta_fn(double n) {
    return exp(lgamma(n / 2.0) + lgamma(0.5) - lgamma((n + 1) / 2.0));
}

extern "C" void kernel_launch(void* const* d_in, const int* in_sizes, int n_in,
                              void* d_out, int out_size, void* d_ws, size_t ws_size,
                              hipStream_t stream) {
    (void)in_sizes; (void)n_in; (void)out_size; (void)ws_size;
    const float* x   = (const float*)d_in[0];
    const float* z1  = (const float*)d_in[1];
    const float* b1  = (const float*)d_in[2];
    const float* z2  = (const float*)d_in[3];
    const float* b2  = (const float*)d_in[4];
    const float* zf1 = (const float*)d_in[5];
    const float* bf1 = (const float*)d_in[6];
    const float* zf2 = (const float*)d_in[7];
    const float* bf2 = (const float*)d_in[8];
    const float* zf3 = (const float*)d_in[9];
    const float* bf3 = (const float*)d_in[10];
    float* out = (float*)d_out;
    float* ws  = (float*)d_ws;

    const float ratio1 = (float)(beta_fn(75.0)  / beta_fn(3.0));
    const float ratio2 = (float)(beta_fn(150.0) / beta_fn(6.0));
    const float ratio3 = (float)(beta_fn(400.0) / beta_fn(16.0));

    float* buf1 = ws + OFF_BUF1;
    float* buf3 = ws + OFF_BUF3;

    prep_kernel<<<236, 64, 0, stream>>>(z1, b1, z2, b2, zf1, bf1, zf2, bf2, zf3, bf3, ws);
    conv1_kernel<<<1024, 256, 0, stream>>>(x, ws, buf1, ratio1);
    conv2_kernel<<<512, 128, 0, stream>>>(buf1, ws, buf3, ratio2, ratio3);
    fc_stack_kernel<<<256, 256, 0, stream>>>(buf3, zf1, zf2, zf3, ws, out);
}

// Round 9
// 175.786 us; speedup vs baseline: 1.0403x; 1.0403x over previous
//
#include <hip/hip_runtime.h>
#include <cmath>

#define EPSF 1e-15f
#define MAXN 0.99999f            // (1 - 1e-5) / sqrt(c), c=1

// ---- workspace layout (float offsets) -------------------------------------
#define OFF_ZU1  0               // 450  normalized z1 columns [75][6]
#define OFF_P1   512             // 18   zn1[6], ch1[6], sh1[6]
#define OFF_ZU2  576             // 2400 normalized z2 columns [150][16]
#define OFF_P2   3072            // 48   zn2[16], ch2[16], sh2[16]
#define OFF_PF1  3200            // 360  znf1[120]*3
#define OFF_PF2  3584            // 252  znf2[84]*3
#define OFF_PF3  3904            // 30   znf3[10]*3

// ---- fast transcendentals -------------------------------------------------
__device__ __forceinline__ float fast_tanh_pos(float x) {   // x >= 0
    float e = __expf(-2.0f * x);
    return (1.0f - e) / (1.0f + e);
}
__device__ __forceinline__ float fast_atanh01(float x) {    // 0 <= x < 1
    return 0.5f * __logf((1.0f + x) / (1.0f - x));
}
// sinh(k * asinh(t)) = sign(t) * 0.5 * (q^k - q^-k), q = |t| + sqrt(t^2+1)
__device__ __forceinline__ float sinh_k_asinh(float t, float k) {
    float at = fabsf(t);
    float lq = __logf(at + sqrtf(fmaf(at, at, 1.0f)));
    float p = __expf(k * lq);
    float r = 0.5f * (p - 1.0f / p);
    return t < 0.f ? -r : r;
}

__device__ __forceinline__ float wave_reduce_sum(float s) {
#pragma unroll
    for (int d = 1; d < 64; d <<= 1) s += __shfl_xor(s, d);
    return s;
}

// block-wide sum over 256 threads; all threads must call.
__device__ __forceinline__ float block_reduce(float v, float* rbuf, int tid) {
    float s = wave_reduce_sum(v);
    __syncthreads();                       // protect rbuf from previous use
    if ((tid & 63) == 0) rbuf[tid >> 6] = s;
    __syncthreads();
    return rbuf[0] + rbuf[1] + rbuf[2] + rbuf[3];
}

// ---------------------------------------------------------------------------
// P0: combined weight prep. One block (64 thr) per output column.
// ---------------------------------------------------------------------------
__global__ __launch_bounds__(64) void prep_kernel(
        const float* __restrict__ z1, const float* __restrict__ r1,
        const float* __restrict__ z2, const float* __restrict__ r2,
        const float* __restrict__ zf1, const float* __restrict__ rf1,
        const float* __restrict__ zf2, const float* __restrict__ rf2,
        const float* __restrict__ zf3, const float* __restrict__ rf3,
        float* __restrict__ ws) {
    int blk = blockIdx.x, lane = threadIdx.x;
    const float* z; const float* r; int Din, Dout, o;
    float* zu = nullptr; float* par;
    if (blk < 6)        { z = z1;  r = r1;  Din = 75;  Dout = 6;   o = blk;       zu = ws + OFF_ZU1; par = ws + OFF_P1; }
    else if (blk < 22)  { z = z2;  r = r2;  Din = 150; Dout = 16;  o = blk - 6;   zu = ws + OFF_ZU2; par = ws + OFF_P2; }
    else if (blk < 142) { z = zf1; r = rf1; Din = 400; Dout = 120; o = blk - 22;  par = ws + OFF_PF1; }
    else if (blk < 226) { z = zf2; r = rf2; Din = 120; Dout = 84;  o = blk - 142; par = ws + OFF_PF2; }
    else                { z = zf3; r = rf3; Din = 84;  Dout = 10;  o = blk - 226; par = ws + OFF_PF3; }
    float s = 0.f;
    for (int f = lane; f < Din; f += 64) { float w = z[f * Dout + o]; s += w * w; }
    s = wave_reduce_sum(s);
    float zn = fmaxf(sqrtf(s), EPSF);
    if (lane == 0) {
        par[o] = zn;
        par[Dout + o]     = coshf(2.0f * r[o]);
        par[2 * Dout + o] = sinhf(2.0f * r[o]);
    }
    if (zu)
        for (int f = lane; f < Din; f += 64) zu[f * Dout + o] = z[f * Dout + o] / zn;
}

// ---------------------------------------------------------------------------
// chain (all channels in-thread): expmap0 -> poincare_fc -> project -> hrelu.
// ---------------------------------------------------------------------------
template<int N>
__device__ __forceinline__ float chain_fast(float (&a)[N], float n2,
        const float (&zn)[N], const float (&ch)[N], const float (&sh)[N]) {
    float nn = fmaxf(sqrtf(n2), EPSF);
    float t = fast_tanh_pos(nn);
    float s = t / nn * fminf(1.0f, MAXN / fmaxf(t, EPSF));
    float cx2 = (s * s) * n2;
    float denom = fmaxf(1.0f - cx2, EPSF);
    float ys2 = 0.f;
#pragma unroll
    for (int o = 0; o < N; o++) {
        float arg = (2.0f * (s * a[o]) * ch[o] - (1.0f + cx2) * sh[o]) / denom;
        float yy = sinh_k_asinh(arg, 2.0f * zn[o]);
        a[o] = yy; ys2 += yy * yy;
    }
    float dnm = 1.0f + sqrtf(1.0f + ys2);
    float ny2 = ys2 / (dnm * dnm);
    float ny = fmaxf(sqrtf(ny2), EPSF);
    float pf = fminf(1.0f, MAXN / ny);
    float sc = pf / dnm;
    float n2b = pf * pf * ny2;
    float nb = fmaxf(sqrtf(n2b), EPSF);
    float fb = fast_atanh01(fminf(nb, 1.0f - 1e-7f)) / nb;
    float m2 = 0.f;
#pragma unroll
    for (int o = 0; o < N; o++) { float uu = fmaxf(fb * sc * a[o], 0.f); a[o] = uu; m2 += uu * uu; }
    float m = fmaxf(sqrtf(m2), EPSF);
    float tm = fast_tanh_pos(m);
    float g = tm / m * fminf(1.0f, MAXN / fmaxf(tm, EPSF));
#pragma unroll
    for (int o = 0; o < N; o++) a[o] *= g;
    return g * g * m2;
}

// ---------------------------------------------------------------------------
// FC layer, block-level. 2 threads per output column (half-dots, combined by
// lane-pair shuffle). dst gets pre-g values for RELU layers (g folded into
// the NEXT layer via gnext); final layer writes sc*y directly.
// ---------------------------------------------------------------------------
template<int DIN, int DOUT, bool RELU>
__device__ __forceinline__ float fc_block(int tid, const float* __restrict__ xin,
        float gin, float cx2, const float* __restrict__ zg,
        const float* __restrict__ parw, float* __restrict__ dst,
        float* rbuf, float& gnext) {
    constexpr int H = DIN / 2;            // DIN even for all layers
    int col = tid >> 1, half = tid & 1;
    bool act = tid < 2 * DOUT;
    float d = 0.f;
    if (act) {
        float a0 = 0.f, a1 = 0.f;
        int f0 = half * H;
        for (int f = f0; f < f0 + H; f += 2) {
            a0 = fmaf(xin[f],     zg[f * DOUT + col],       a0);
            a1 = fmaf(xin[f + 1], zg[(f + 1) * DOUT + col], a1);
        }
        d = a0 + a1;
    }
    d += __shfl_xor(d, 1);                // combine halves (pairs aligned)
    d *= gin;
    float y = 0.f;
    float denom = fmaxf(1.0f - cx2, EPSF);
    if (act) {
        float zn = parw[col], chv = parw[DOUT + col], shv = parw[2 * DOUT + col];
        float arg = (2.0f * (d / zn) * chv - (1.0f + cx2) * shv) / denom;
        y = sinh_k_asinh(arg, 2.0f * zn);
    }
    float ys2 = block_reduce((act && half == 0) ? y * y : 0.f, rbuf, tid);
    float dnm = 1.0f + sqrtf(1.0f + ys2);
    float ny2 = ys2 / (dnm * dnm);
    float ny = fmaxf(sqrtf(ny2), EPSF);
    float pf = fminf(1.0f, MAXN / ny);
    float sc = pf / dnm;
    if (!RELU) {
        if (act && half == 0) dst[col] = sc * y;
        gnext = 1.f;
        return 0.f;
    }
    float n2b = pf * pf * ny2;
    float nb = fmaxf(sqrtf(n2b), EPSF);
    float fb = fast_atanh01(fminf(nb, 1.0f - 1e-7f)) / nb;
    float u = fmaxf(fb * sc * y, 0.f);
    if (act && half == 0) dst[col] = u;   // pre-g; next barrier publishes
    float m2 = block_reduce((act && half == 0) ? u * u : 0.f, rbuf, tid);
    float m = fmaxf(sqrtf(m2), EPSF);
    float tm = fast_tanh_pos(m);
    float g = tm / m * fminf(1.0f, MAXN / fmaxf(tm, EPSF));
    gnext = g;
    return g * g * m2;
}

// ---------------------------------------------------------------------------
// MEGA: whole net, one block per image.
// ---------------------------------------------------------------------------
__global__ __launch_bounds__(256) void mega_kernel(const float* __restrict__ x,
        const float* __restrict__ ws, const float* __restrict__ zf1,
        const float* __restrict__ zf2, const float* __restrict__ zf3,
        float* __restrict__ out, float ratio1, float ratio2, float ratio3) {
    __shared__ float xv[3168];            // [3][32][33]
    __shared__ float z2s[2400];           // z2 unit columns [150][16]
    __shared__ float par2[48];
    __shared__ float v2[1260];            // conv1 out, logmap'd [6][14][15]
    __shared__ float rs[140];             // conv2 patch-norm row sums [14][10]
    __shared__ float u3[400];             // flatten (pre-g)
    __shared__ float h1[120];
    __shared__ float h2[84];
    __shared__ float spart[5];
    __shared__ float rbuf[4];
    int b = blockIdx.x, tid = threadIdx.x;

    // ---- A: stage input + conv2 weights ----
    for (int i = tid; i < 3072; i += 256) {
        int c = i >> 10, rem = i & 1023;
        xv[c * 1056 + (rem >> 5) * 33 + (rem & 31)] = x[(size_t)b * 3072 + i];
    }
    for (int i = tid; i < 2400; i += 256) z2s[i] = ws[OFF_ZU2 + i];
    if (tid < 48) par2[tid] = ws[OFF_P2 + tid];
    __syncthreads();

    // ---- B: logmap0 over channels of x ----
    for (int p = tid; p < 1024; p += 256) {
        int base = (p >> 5) * 33 + (p & 31);
        float a0 = xv[base], a1 = xv[1056 + base], a2 = xv[2112 + base];
        float n2 = a0 * a0 + a1 * a1 + a2 * a2;
        float nn = fmaxf(sqrtf(n2), EPSF);
        float f = fast_atanh01(fminf(nn, 1.0f - 1e-7f)) / nn * ratio1;
        xv[base] = a0 * f; xv[1056 + base] = a1 * f; xv[2112 + base] = a2 * f;
    }
    __syncthreads();

    // ---- C: conv1 + hrelu + pool (thread = pooled cell), fused logmap2 ----
    if (tid < 196) {
        const float* zug  = ws + OFF_ZU1;
        const float* parg = ws + OFF_P1;
        int ph = tid / 14, pw = tid % 14;
        int base0 = (2 * ph) * 33 + 2 * pw;
        float acc[4][6], n2w[4];
#pragma unroll
        for (int wi = 0; wi < 4; wi++) {
            n2w[wi] = 0.f;
#pragma unroll
            for (int o = 0; o < 6; o++) acc[wi][o] = 0.f;
        }
#pragma unroll 1
        for (int c = 0; c < 3; c++) {
            float px[6][6];
#pragma unroll
            for (int r = 0; r < 6; r++)
#pragma unroll
            for (int j = 0; j < 6; j++)
                px[r][j] = xv[c * 1056 + base0 + r * 33 + j];
#pragma unroll
            for (int fi = 0; fi < 5; fi++) {
                const float* zp = zug + (c * 5 + fi) * 30;   // wave-uniform
#pragma unroll
                for (int fj = 0; fj < 5; fj++) {
                    float zw[6];
#pragma unroll
                    for (int o = 0; o < 6; o++) zw[o] = zp[fj * 6 + o];
#pragma unroll
                    for (int dy = 0; dy < 2; dy++)
#pragma unroll
                    for (int dx = 0; dx < 2; dx++) {
                        float v = px[fi + dy][fj + dx];
                        int wi = dy * 2 + dx;
                        n2w[wi] = fmaf(v, v, n2w[wi]);
#pragma unroll
                        for (int o = 0; o < 6; o++) acc[wi][o] = fmaf(v, zw[o], acc[wi][o]);
                    }
                }
            }
        }
        float zn[6], chv[6], shv[6];
#pragma unroll
        for (int o = 0; o < 6; o++) { zn[o] = parg[o]; chv[o] = parg[6 + o]; shv[o] = parg[12 + o]; }
        float best[6]; float bestn = -1.f;
#pragma unroll
        for (int wi = 0; wi < 4; wi++) {
            float hn2 = chain_fast<6>(acc[wi], n2w[wi], zn, chv, shv);
            if (hn2 > bestn) {
                bestn = hn2;
#pragma unroll
                for (int o = 0; o < 6; o++) best[o] = acc[wi][o];
            }
        }
        float nn = fmaxf(sqrtf(bestn), EPSF);
        float f2 = fast_atanh01(fminf(nn, 1.0f - 1e-7f)) / nn * ratio2;
#pragma unroll
        for (int o = 0; o < 6; o++) v2[o * 210 + ph * 15 + pw] = f2 * best[o];
    }
    __syncthreads();

    // ---- D: conv2 patch-norm row sums rs[r][x] = sum_c sum_j v2[c][r][x+j]^2
    if (tid < 140) {
        int r = tid / 10, xq = tid % 10;
        float ssum = 0.f;
#pragma unroll
        for (int c = 0; c < 6; c++)
#pragma unroll
        for (int j = 0; j < 5; j++) {
            float v = v2[c * 210 + r * 15 + xq + j];
            ssum = fmaf(v, v, ssum);
        }
        rs[tid] = ssum;
    }
    __syncthreads();

    // ---- E: conv2 + hrelu + pool + flatten. thread = (window-row wy, chan o)
    if (tid < 160) {
        int wy = tid >> 4, o = tid & 15;
        float acc[10];
#pragma unroll
        for (int w = 0; w < 10; w++) acc[w] = 0.f;
#pragma unroll 1
        for (int c = 0; c < 6; c++) {
#pragma unroll 1
            for (int fi = 0; fi < 5; fi++) {
                float px[14];
#pragma unroll
                for (int k = 0; k < 14; k++) px[k] = v2[c * 210 + (wy + fi) * 15 + k];
#pragma unroll
                for (int fj = 0; fj < 5; fj++) {
                    float zw = z2s[((c * 5 + fi) * 5 + fj) * 16 + o];
#pragma unroll
                    for (int w = 0; w < 10; w++)
                        acc[w] = fmaf(px[w + fj], zw, acc[w]);
                }
            }
        }
        float znl = par2[o], chv = par2[16 + o], shv = par2[32 + o];
        float val[10], hn2v[10];
#pragma unroll
        for (int w = 0; w < 10; w++) {
            float n2 = rs[wy * 10 + w] + rs[(wy + 1) * 10 + w] + rs[(wy + 2) * 10 + w]
                     + rs[(wy + 3) * 10 + w] + rs[(wy + 4) * 10 + w];
            float nn = fmaxf(sqrtf(n2), EPSF);
            float t = fast_tanh_pos(nn);
            float s = t / nn * fminf(1.0f, MAXN / fmaxf(t, EPSF));
            float cx2 = (s * s) * n2;
            float denom = fmaxf(1.0f - cx2, EPSF);
            float arg = (2.0f * (s * acc[w]) * chv - (1.0f + cx2) * shv) / denom;
            float y = sinh_k_asinh(arg, 2.0f * znl);
            float p = y * y;
#pragma unroll
            for (int d = 1; d < 16; d <<= 1) p += __shfl_xor(p, d);
            float ys2 = p;
            float dnm = 1.0f + sqrtf(1.0f + ys2);
            float ny2 = ys2 / (dnm * dnm);
            float ny = fmaxf(sqrtf(ny2), EPSF);
            float pf = fminf(1.0f, MAXN / ny);
            float sc = pf / dnm;
            float n2b = pf * pf * ny2;
            float nb = fmaxf(sqrtf(n2b), EPSF);
            float fb = fast_atanh01(fminf(nb, 1.0f - 1e-7f)) / nb;
            float u = fmaxf(fb * sc * y, 0.f);
            float q = u * u;
#pragma unroll
            for (int d = 1; d < 16; d <<= 1) q += __shfl_xor(q, d);
            float m2 = q;
            float m = fmaxf(sqrtf(m2), EPSF);
            float tm = fast_tanh_pos(m);
            float g = tm / m * fminf(1.0f, MAXN / fmaxf(tm, EPSF));
            val[w] = g * u;
            hn2v[w] = g * g * m2;
        }
        // pool 2x2 (first-max semantics) + flatten logmap factor
        float part = 0.f;
#pragma unroll
        for (int pw = 0; pw < 5; pw++) {
            int i0 = 2 * pw, i1 = i0 + 1;
            bool firstcol = hn2v[i0] >= hn2v[i1];
            float iu = firstcol ? val[i0]  : val[i1];
            float ih = firstcol ? hn2v[i0] : hn2v[i1];
            float pu  = __shfl_xor(iu, 16);   // partner row (wy ^ 1)
            float phh = __shfl_xor(ih, 16);
            if ((wy & 1) == 0) {
                bool top = ih >= phh;
                float wu = top ? iu : pu;
                float wh = top ? ih : phh;
                float nn = fmaxf(sqrtf(wh), EPSF);
                float f3 = fast_atanh01(fminf(nn, 1.0f - 1e-7f)) / nn * ratio3;
                u3[o * 25 + (wy >> 1) * 5 + pw] = f3 * wu;
                if (o == 0) part = fmaf(f3 * f3, wh, part);
            }
        }
        if ((wy & 1) == 0 && o == 0) spart[wy >> 1] = part;
    }
    __syncthreads();

    // ---- F: flatten expmap scale + FC stack ----
    float S = spart[0] + spart[1] + spart[2] + spart[3] + spart[4];
    float nnS = fmaxf(sqrtf(S), EPSF);
    float tS = fast_tanh_pos(nnS);
    float gflat = tS / nnS * fminf(1.0f, MAXN / fmaxf(tS, EPSF));
    float cx2a = gflat * gflat * S;

    float g1, g2, gd;
    float cx2b = fc_block<400, 120, true >(tid, u3, gflat, cx2a, zf1, ws + OFF_PF1, h1, rbuf, g1);
    float cx2c = fc_block<120, 84,  true >(tid, h1, g1,   cx2b, zf2, ws + OFF_PF2, h2, rbuf, g2);
    fc_block<84, 10, false>(tid, h2, g2, cx2c, zf3, ws + OFF_PF3, out + (size_t)b * 10, rbuf, gd);
}

// ---------------------------------------------------------------------------
static double beta_fn(double n) {
    return exp(lgamma(n / 2.0) + lgamma(0.5) - lgamma((n + 1) / 2.0));
}

extern "C" void kernel_launch(void* const* d_in, const int* in_sizes, int n_in,
                              void* d_out, int out_size, void* d_ws, size_t ws_size,
                              hipStream_t stream) {
    (void)in_sizes; (void)n_in; (void)out_size; (void)ws_size;
    const float* x   = (const float*)d_in[0];
    const float* z1  = (const float*)d_in[1];
    const float* b1  = (const float*)d_in[2];
    const float* z2  = (const float*)d_in[3];
    const float* b2  = (const float*)d_in[4];
    const float* zf1 = (const float*)d_in[5];
    const float* bf1 = (const float*)d_in[6];
    const float* zf2 = (const float*)d_in[7];
    const float* bf2 = (const float*)d_in[8];
    const float* zf3 = (const float*)d_in[9];
    const float* bf3 = (const float*)d_in[10];
    float* out = (float*)d_out;
    float* ws  = (float*)d_ws;

    const float ratio1 = (float)(beta_fn(75.0)  / beta_fn(3.0));
    const float ratio2 = (float)(beta_fn(150.0) / beta_fn(6.0));
    const float ratio3 = (float)(beta_fn(400.0) / beta_fn(16.0));

    prep_kernel<<<236, 64, 0, stream>>>(z1, b1, z2, b2, zf1, bf1, zf2, bf2, zf3, bf3, ws);
    mega_kernel<<<1024, 256, 0, stream>>>(x, ws, zf1, zf2, zf3, out,
                                          ratio1, ratio2, ratio3);
}